// Round 1
// baseline (362.713 us; speedup 1.0000x reference)
//
#include <hip/hip_runtime.h>

#define DD 2048
#define SS 8192
#define BB 8
#define TWO_D 4096

// ---------------------------------------------------------------------------
// k1_gate: one spine-update iteration's gate matvec.
// Grid: 256 blocks x 256 threads. Block handles 8 output columns (4 waves x 2).
// LDS stages v (phase A) then z (phase B) for all 8 batches: 8x2048 f32 = 64KiB.
// Writes u = g*v + (1-g)*z  (pre-layernorm) to u_out[8][2048].
// ---------------------------------------------------------------------------
__global__ __launch_bounds__(256) void k1_gate(
    const float* __restrict__ x, int pz,
    const float* __restrict__ ybase, unsigned long long ybstr,
    const float* __restrict__ pbase, unsigned long long pbstr,
    const float* __restrict__ a_xz, const float* __restrict__ b_xy, const float* __restrict__ g_x,
    const float* __restrict__ a_wy, const float* __restrict__ b_wx, const float* __restrict__ g_w,
    const float* __restrict__ a_xv, const float* __restrict__ b_wv, const float* __restrict__ g_v,
    const float* __restrict__ gate_w, const float* __restrict__ gate_b,
    float* __restrict__ u_out)
{
    __shared__ float lds[BB][DD];   // 64 KiB
    const int tid = threadIdx.x;
    const size_t bstr_x = (size_t)SS * DD;
    const float* zrow = x + (size_t)pz * DD;   // z rows always come from original x

    // Phase 1: compute v into LDS for all 8 batches.
    for (int dd = 0; dd < DD; dd += 256) {
        const int d = dd + tid;
        const float axz = a_xz[d], bxy = b_xy[d], gx  = g_x[d];
        const float awy = a_wy[d], bwx = b_wx[d], gww = g_w[d];
        const float axv = a_xv[d], bwv = b_wv[d], gv  = g_v[d];
#pragma unroll
        for (int b = 0; b < BB; ++b) {
            const float z  = zrow[(size_t)b * bstr_x + d];
            const float y  = ybase[(size_t)b * ybstr + d];
            const float xp = pbase[(size_t)b * pbstr + d];
            const float xn = axz * z + bxy * y + gx;
            const float w  = awy * y + bwx * xp + gww;
            lds[b][d] = axv * xn + bwv * w + gv;
        }
    }
    __syncthreads();

    const int wave = tid >> 6, lane = tid & 63;
    const int d0 = blockIdx.x * 8 + wave * 2;      // this wave's two output columns
    float acc0[BB], acc1[BB];
#pragma unroll
    for (int b = 0; b < BB; ++b) { acc0[b] = 0.f; acc1[b] = 0.f; }

    const float* gw0 = gate_w + (size_t)d0 * TWO_D;
    const float* gw1 = gate_w + (size_t)(d0 + 1) * TWO_D;

    // Phase 2a: j in [0, D) -> v part
    for (int j = lane * 4; j < DD; j += 256) {
        const float4 w0 = *(const float4*)(gw0 + j);
        const float4 w1 = *(const float4*)(gw1 + j);
#pragma unroll
        for (int b = 0; b < BB; ++b) {
            const float4 vv = *(const float4*)&lds[b][j];
            acc0[b] += w0.x * vv.x + w0.y * vv.y + w0.z * vv.z + w0.w * vv.w;
            acc1[b] += w1.x * vv.x + w1.y * vv.y + w1.z * vv.z + w1.w * vv.w;
        }
    }
    const int myb = lane & 7, myc = lane >> 3;
    const float vmine = (lane < 16) ? lds[myb][d0 + myc] : 0.f;
    __syncthreads();

    // Reload LDS with z rows.
    for (int dd = 0; dd < DD; dd += 256) {
        const int d = dd + tid;
#pragma unroll
        for (int b = 0; b < BB; ++b)
            lds[b][d] = zrow[(size_t)b * bstr_x + d];
    }
    __syncthreads();

    // Phase 2b: j in [D, 2D) -> z part
    for (int j = lane * 4; j < DD; j += 256) {
        const float4 w0 = *(const float4*)(gw0 + DD + j);
        const float4 w1 = *(const float4*)(gw1 + DD + j);
#pragma unroll
        for (int b = 0; b < BB; ++b) {
            const float4 zz = *(const float4*)&lds[b][j];
            acc0[b] += w0.x * zz.x + w0.y * zz.y + w0.z * zz.z + w0.w * zz.w;
            acc1[b] += w1.x * zz.x + w1.y * zz.y + w1.z * zz.z + w1.w * zz.w;
        }
    }
    const float zmine = (lane < 16) ? lds[myb][d0 + myc] : 0.f;

    // Butterfly reduce all 16 accumulators across the 64-lane wave.
#pragma unroll
    for (int b = 0; b < BB; ++b) {
#pragma unroll
        for (int off = 32; off >= 1; off >>= 1) {
            acc0[b] += __shfl_xor(acc0[b], off);
            acc1[b] += __shfl_xor(acc1[b], off);
        }
    }

    if (lane < 16) {
        float sacc = 0.f;
#pragma unroll
        for (int b = 0; b < BB; ++b)
            if (b == myb) sacc = myc ? acc1[b] : acc0[b];
        const int d = d0 + myc;
        const float g = 1.f / (1.f + expf(-(sacc + gate_b[d])));
        u_out[myb * DD + d] = g * vmine + (1.f - g) * zmine;
    }
}

// ---------------------------------------------------------------------------
// k2_ln: layernorm the 8 rows of u, write to this iteration's result buffer.
// Grid: 8 blocks x 256 threads (one block per batch row).
// ---------------------------------------------------------------------------
__global__ __launch_bounds__(256) void k2_ln(
    const float* __restrict__ u, const float* __restrict__ lnw,
    const float* __restrict__ lnb, float* __restrict__ dst)
{
    const int b = blockIdx.x, tid = threadIdx.x;
    const float* ub = u + b * DD;
    float vals[8];
    float s = 0.f, sq = 0.f;
#pragma unroll
    for (int i = 0; i < 8; ++i) {
        const float t = ub[tid + 256 * i];
        vals[i] = t; s += t; sq += t * t;
    }
    const int wave = tid >> 6, lane = tid & 63;
#pragma unroll
    for (int off = 32; off >= 1; off >>= 1) {
        s  += __shfl_xor(s, off);
        sq += __shfl_xor(sq, off);
    }
    __shared__ float red[2][4];
    if (lane == 0) { red[0][wave] = s; red[1][wave] = sq; }
    __syncthreads();
    s  = red[0][0] + red[0][1] + red[0][2] + red[0][3];
    sq = red[1][0] + red[1][1] + red[1][2] + red[1][3];
    const float mean = s * (1.f / DD);
    const float var  = sq * (1.f / DD) - mean * mean;
    const float rs   = rsqrtf(var + 1e-5f);
    float* db = dst + b * DD;
#pragma unroll
    for (int i = 0; i < 8; ++i) {
        const int d = tid + 256 * i;
        db[d] = (vals[i] - mean) * rs * lnw[d] + lnb[d];
    }
}

// ---------------------------------------------------------------------------
// k3_copy: x -> out, float4 grid-stride. The HBM-bound bulk of the problem.
// ---------------------------------------------------------------------------
__global__ __launch_bounds__(256) void k3_copy(
    const float4* __restrict__ src, float4* __restrict__ dst, size_t n4)
{
    size_t i = (size_t)blockIdx.x * blockDim.x + threadIdx.x;
    const size_t stride = (size_t)gridDim.x * blockDim.x;
    for (; i < n4; i += stride) dst[i] = src[i];
}

// ---------------------------------------------------------------------------
// k4_inject: scatter the 7 updated (layernormed) rows into out.
// Grid: (7*8*2048)/256 blocks.
// ---------------------------------------------------------------------------
__global__ __launch_bounds__(256) void k4_inject(
    const float* __restrict__ res, float* __restrict__ out)
{
    const int idx = blockIdx.x * 256 + threadIdx.x;   // < 7*8*2048
    const int it = idx >> 14;           // 8*2048 = 16384
    const int r  = idx & 16383;
    const int b  = r >> 11;
    const int d  = r & 2047;
    const int pz = it == 0 ? 12 : it == 1 ? 36 : it == 2 ? 104 : it == 3 ? 304
                 : it == 4 ? 888 : it == 5 ? 2592 : 7568;
    out[(size_t)b * SS * DD + (size_t)pz * DD + d] = res[idx];
}

extern "C" void kernel_launch(void* const* d_in, const int* in_sizes, int n_in,
                              void* d_out, int out_size, void* d_ws, size_t ws_size,
                              hipStream_t stream)
{
    const float* x      = (const float*)d_in[0];
    const float* a_xz   = (const float*)d_in[1];
    const float* b_xy   = (const float*)d_in[2];
    const float* g_x    = (const float*)d_in[3];
    const float* a_wy   = (const float*)d_in[4];
    const float* b_wx   = (const float*)d_in[5];
    const float* g_w    = (const float*)d_in[6];
    const float* a_xv   = (const float*)d_in[7];
    const float* b_wv   = (const float*)d_in[8];
    const float* g_v    = (const float*)d_in[9];
    const float* gate_w = (const float*)d_in[10];
    const float* gate_b = (const float*)d_in[11];
    const float* ln_w   = (const float*)d_in[12];
    const float* ln_b   = (const float*)d_in[13];
    float* out = (float*)d_out;

    float* u_buf = (float*)d_ws;           // 8*2048 f32 scratch (pre-LN)
    float* res   = u_buf + BB * DD;        // 7 * 8*2048 f32 updated rows

    // spine: [0,2,4,12,36,104,304,888,2592,7568]; iterations k=3..9
    static const int PZ[7] = {12, 36, 104, 304, 888, 2592, 7568};
    static const int PY[7] = {4, 12, 36, 104, 304, 888, 2592};
    static const int PX[7] = {2, 4, 12, 36, 104, 304, 888};

    for (int it = 0; it < 7; ++it) {
        const float* ybase; unsigned long long ybstr;
        const float* pbase; unsigned long long pbstr;
        if (it == 0) { ybase = x + (size_t)PY[0] * DD; ybstr = (size_t)SS * DD; }
        else         { ybase = res + (size_t)(it - 1) * BB * DD; ybstr = DD; }
        if (it <= 1) { pbase = x + (size_t)PX[it] * DD; pbstr = (size_t)SS * DD; }
        else         { pbase = res + (size_t)(it - 2) * BB * DD; pbstr = DD; }

        hipLaunchKernelGGL(k1_gate, dim3(DD / 8), dim3(256), 0, stream,
                           x, PZ[it], ybase, ybstr, pbase, pbstr,
                           a_xz, b_xy, g_x, a_wy, b_wx, g_w, a_xv, b_wv, g_v,
                           gate_w, gate_b, u_buf);
        hipLaunchKernelGGL(k2_ln, dim3(BB), dim3(256), 0, stream,
                           u_buf, ln_w, ln_b, res + (size_t)it * BB * DD);
    }

    const size_t n4 = (size_t)out_size / 4;
    hipLaunchKernelGGL(k3_copy, dim3(2048), dim3(256), 0, stream,
                       (const float4*)x, (float4*)out, n4);
    hipLaunchKernelGGL(k4_inject, dim3((7 * BB * DD) / 256), dim3(256), 0, stream,
                       res, out);
}